// Round 16
// baseline (210.386 us; speedup 1.0000x reference)
//
#include <hip/hip_runtime.h>
#include <hip/hip_fp16.h>

// GCN 2-layer. Edges partitioned into 782 static dst-buckets (CAP=4096;
// Binom(1.6M,1/782): mean 2048, sd 45), counting-sorted per bucket by
// (dst_local, src_chunk). rowinfo = (start<<10)|deg. fp16 features (r9),
// masked full-width gather batches (r15), GEMM2 fused into layer-1 agg (r12).
// r16: gemm1 writes UNSCALED Hh so it no longer depends on dinv -> merged
// with k_part into one fat kernel (782 gemm blocks + 782 part blocks run
// concurrently); dinv[src] is applied inside fused48's gather via the
// existing mask-select slot (dinv = 400 KB, L2-resident; r11 proved gather
// instruction count is not the limiter).
// r15 lesson: the serial gather TAIL was the latency chain; masked batches fix.
// r13/r14 lesson: occupancy (grid- or wave-derived) is NOT the agg limiter.
// r8 lesson: non-contiguous feature slicing explodes line traffic.
// r5 lesson: transposed-X LDS staging + full unroll => scratch spill.
// out = GCNConv(relu(GCNConv(x,W1,b1)), W2, b2); N=100k, E=1.6M, 64->48->32.

#define NN 100000
#define NE 1600000
#define NPB 128                         // nodes per bucket
#define NBUCK ((NN + NPB - 1) / NPB)    // 782
#define PBITS 17                        // src fits in 17 bits
#define PMASK ((1 << PBITS) - 1)
#define CHB 3                           // log2 src chunks
#define CHS 14                          // chunk = src >> 14
#define NKEY (NPB << CHB)               // 1024 sort keys per bucket
#define CAP 4096                        // static slots per bucket
#define UN 8                            // agg edge-loop unroll (masked batches)
#define GEMMB ((NN + 127) / 128)        // 782 gemm blocks in fat kernel
#define EPT 8                           // edges/thread in part path (256 thr)
#define PARTB ((NE + 2047) / 2048)      // 782 part blocks in fat kernel

struct alignas(8)  half4 { __half2 lo, hi; };
struct alignas(16) half8 { __half2 a, b, c, d; };

// Fat kernel: blocks [0,GEMMB) run gemm1 (Hh = X @ W1, UNSCALED, fp16 out);
// blocks [GEMMB, GEMMB+PARTB) partition edges into static bucket slots.
// Data-independent workloads overlap in one dispatch.
__global__ __launch_bounds__(256) void
k_fat(const float* __restrict__ X, const float* __restrict__ W,
      __half* __restrict__ Hh,
      const int* __restrict__ src, const int* __restrict__ dst,
      int* __restrict__ cursor, int* __restrict__ packed) {
    __shared__ float w[64 * 48];
    __shared__ int h[NBUCK];
    __shared__ int base[NBUCK];
    int tid = threadIdx.x;
    if (blockIdx.x < GEMMB) {
        // ---------------- gemm1 path: 128 rows, 2 rows x 12 cols/thread ----
        int R0 = blockIdx.x * 128;
        for (int i = tid; i < 64 * 48; i += 256) w[i] = W[i];
        __syncthreads();
        int tc = tid & 3, tr = tid >> 2;
        int r0 = R0 + 2 * tr, r1 = r0 + 1;
        int c0 = tc * 12;
        bool ok0 = r0 < NN, ok1 = r1 < NN;
        const float4* X4 = (const float4*)X;
        const float4 z4 = make_float4(0.f, 0.f, 0.f, 0.f);
        float acc[2][12];
#pragma unroll
        for (int rr = 0; rr < 2; ++rr)
#pragma unroll
            for (int j = 0; j < 12; ++j) acc[rr][j] = 0.f;
#pragma unroll 2
        for (int k4 = 0; k4 < 16; ++k4) {
            float4 xa = ok0 ? X4[(size_t)r0 * 16 + k4] : z4;
            float4 xb = ok1 ? X4[(size_t)r1 * 16 + k4] : z4;
            float ar[4] = {xa.x, xa.y, xa.z, xa.w};
            float br[4] = {xb.x, xb.y, xb.z, xb.w};
#pragma unroll
            for (int j = 0; j < 4; ++j) {
                float va = ar[j], vb = br[j];
#pragma unroll
                for (int q = 0; q < 3; ++q) {
                    float4 wv = *(const float4*)&w[(4 * k4 + j) * 48 + c0 + 4 * q];
                    acc[0][q*4+0] = fmaf(va, wv.x, acc[0][q*4+0]);
                    acc[0][q*4+1] = fmaf(va, wv.y, acc[0][q*4+1]);
                    acc[0][q*4+2] = fmaf(va, wv.z, acc[0][q*4+2]);
                    acc[0][q*4+3] = fmaf(va, wv.w, acc[0][q*4+3]);
                    acc[1][q*4+0] = fmaf(vb, wv.x, acc[1][q*4+0]);
                    acc[1][q*4+1] = fmaf(vb, wv.y, acc[1][q*4+1]);
                    acc[1][q*4+2] = fmaf(vb, wv.z, acc[1][q*4+2]);
                    acc[1][q*4+3] = fmaf(vb, wv.w, acc[1][q*4+3]);
                }
            }
        }
#pragma unroll
        for (int rr = 0; rr < 2; ++rr) {
            int gr = r0 + rr;
            if (gr >= NN) continue;
#pragma unroll
            for (int q = 0; q < 3; ++q) {
                __half2 p0 = __floats2half2_rn(acc[rr][q*4+0], acc[rr][q*4+1]);
                __half2 p1 = __floats2half2_rn(acc[rr][q*4+2], acc[rr][q*4+3]);
                half4 hv; hv.lo = p0; hv.hi = p1;
                *(half4*)(Hh + (size_t)gr * 48 + c0 + 4 * q) = hv;
            }
        }
    } else {
        // ---------------- part path: 2048 edges/block into bucket slots ----
        int pb = blockIdx.x - GEMMB;
        for (int i = tid; i < NBUCK; i += 256) h[i] = 0;
        __syncthreads();
        int ebase = pb * 2048;
        for (int k = 0; k < EPT; ++k) {
            int e = ebase + k * 256 + tid;
            if (e < NE) atomicAdd(&h[dst[e] >> 7], 1);
        }
        __syncthreads();
        for (int i = tid; i < NBUCK; i += 256) {
            int c = h[i];
            if (c) base[i] = atomicAdd(&cursor[i], c);
            h[i] = 0;
        }
        __syncthreads();
        for (int k = 0; k < EPT; ++k) {
            int e = ebase + k * 256 + tid;
            if (e < NE) {
                int d = dst[e];
                int b = d >> 7;
                int r = atomicAdd(&h[b], 1);
                packed[(size_t)b * CAP + base[b] + r] = src[e] | ((d & (NPB - 1)) << PBITS);
            }
        }
    }
}

// per-bucket counting sort by (dst_local, src_chunk) -> srcsort (bucket-padded),
// rowinfo = (global_start << 10) | deg, dinv = rsqrt(deg+1).
__global__ void k_bsort(const int* __restrict__ packed, const int* __restrict__ cursor,
                        int* __restrict__ srcsort, unsigned int* __restrict__ rowinfo,
                        float* __restrict__ dinv) {
    __shared__ int stage[CAP];          // 16 KB (sz <= CAP always)
    __shared__ int cnt[NKEY];           // 4 KB
    __shared__ int tsum[256];
    int tid = threadIdx.x, b = blockIdx.x;
    int e0 = b * CAP, sz = cursor[b];
    for (int i = tid; i < NKEY; i += 256) cnt[i] = 0;
    __syncthreads();
    for (int i = tid; i < sz; i += 256) {
        int w = packed[e0 + i];
        stage[i] = w;
        int key = ((w >> PBITS) << CHB) | ((w & PMASK) >> CHS);
        atomicAdd(&cnt[key], 1);
    }
    __syncthreads();
    int k0 = tid * 4;
    int c0 = cnt[k0], c1 = cnt[k0 + 1], c2 = cnt[k0 + 2], c3 = cnt[k0 + 3];
    int loc = c0 + c1 + c2 + c3;
    tsum[tid] = loc;
    __syncthreads();
    for (int off = 1; off < 256; off <<= 1) {
        int v = (tid >= off) ? tsum[tid - off] : 0;
        __syncthreads();
        tsum[tid] += v;
        __syncthreads();
    }
    int base = tsum[tid] - loc;
    cnt[k0]     = base;
    cnt[k0 + 1] = base + c0;
    cnt[k0 + 2] = base + c0 + c1;
    cnt[k0 + 3] = base + c0 + c1 + c2;
    __syncthreads();
    if (tid < NPB) {
        int node = b * NPB + tid;
        int rs = cnt[tid << CHB];
        int re = (tid == NPB - 1) ? sz : cnt[(tid + 1) << CHB];
        if (node < NN) {
            rowinfo[node] = ((unsigned int)(e0 + rs) << 10) | (unsigned int)(re - rs);
            dinv[node] = rsqrtf((float)(re - rs + 1));   // +1 self-loop
        }
    }
    __syncthreads();
    for (int i = tid; i < sz; i += 256) {
        int w = stage[i];
        int key = ((w >> PBITS) << CHB) | ((w & PMASK) >> CHS);
        int p = atomicAdd(&cnt[key], 1);
        srcsort[e0 + p] = w & PMASK;
    }
}

// Fused layer-1 aggregation + relu/b1 + GEMM2 + dinv. 128-row tile, 256 thr.
// Hh is UNSCALED: per-edge weight dinv[src] rides the mask-select slot
// (m = ok ? dinv[ss] : 0); self-term scaled by dinv[r] in-register.
// Phase-2 output pre-scaled by dinv[gr] so agg32 stays unchanged.
__global__ __launch_bounds__(256) void
k_fused48(const __half* __restrict__ Hh, const unsigned int* __restrict__ rowinfo,
          const int* __restrict__ srcsort, const float* __restrict__ dinv,
          const float* __restrict__ b1, const float* __restrict__ W2,
          __half* __restrict__ Hh2) {
    constexpr int ROWS = 128, XS = 49;
    __shared__ float Xs[ROWS * XS];      // 25088 B
    __shared__ float w2[48 * 32];        // 6144 B
    __shared__ float bb[48];
    int tid = threadIdx.x;
    int R0 = blockIdx.x * ROWS;
    for (int i = tid; i < 48 * 32; i += 256) w2[i] = W2[i];
    if (tid < 48) bb[tid] = b1[tid];
    __syncthreads();

    // ---- phase 1: aggregate into Xs (3 (row,chunk) items per thread) ----
    for (int t = tid; t < ROWS * 6; t += 256) {
        int lr = t / 6, q = t - lr * 6;
        int r = R0 + lr;
        if (r >= NN) continue;
        float d = dinv[r];
        half8 sv = *(const half8*)(Hh + (size_t)r * 48 + 8 * q);   // self (raw)
        float2 f0 = __half22float2(sv.a), f1 = __half22float2(sv.b);
        float2 f2 = __half22float2(sv.c), f3 = __half22float2(sv.d);
        float a0 = f0.x * d, a1 = f0.y * d, a2 = f1.x * d, a3 = f1.y * d;
        float a4 = f2.x * d, a5 = f2.y * d, a6 = f3.x * d, a7 = f3.y * d;
        unsigned int rp = rowinfo[r];
        int e0 = rp >> 10, e1 = e0 + (int)(rp & 1023);
        for (int e = e0; e < e1; e += UN) {
            int ss[UN]; bool okb[UN];
#pragma unroll
            for (int u = 0; u < UN; ++u) {
                int ee = e + u;
                okb[u] = ee < e1;
                ss[u] = srcsort[okb[u] ? ee : e0];
            }
            float dd[UN];
#pragma unroll
            for (int u = 0; u < UN; ++u) dd[u] = dinv[ss[u]];  // L2-resident
            half8 vv[UN];
#pragma unroll
            for (int u = 0; u < UN; ++u)
                vv[u] = *(const half8*)(Hh + (size_t)ss[u] * 48 + 8 * q);
#pragma unroll
            for (int u = 0; u < UN; ++u) {
                float m = okb[u] ? dd[u] : 0.f;
                float2 g0 = __half22float2(vv[u].a), g1 = __half22float2(vv[u].b);
                float2 g2 = __half22float2(vv[u].c), g3 = __half22float2(vv[u].d);
                a0 = fmaf(g0.x, m, a0); a1 = fmaf(g0.y, m, a1);
                a2 = fmaf(g1.x, m, a2); a3 = fmaf(g1.y, m, a3);
                a4 = fmaf(g2.x, m, a4); a5 = fmaf(g2.y, m, a5);
                a6 = fmaf(g3.x, m, a6); a7 = fmaf(g3.y, m, a7);
            }
        }
        float* xr = &Xs[lr * XS + 8 * q];
        const float* bf = &bb[8 * q];
        xr[0] = fmaxf(fmaf(a0, d, bf[0]), 0.f);
        xr[1] = fmaxf(fmaf(a1, d, bf[1]), 0.f);
        xr[2] = fmaxf(fmaf(a2, d, bf[2]), 0.f);
        xr[3] = fmaxf(fmaf(a3, d, bf[3]), 0.f);
        xr[4] = fmaxf(fmaf(a4, d, bf[4]), 0.f);
        xr[5] = fmaxf(fmaf(a5, d, bf[5]), 0.f);
        xr[6] = fmaxf(fmaf(a6, d, bf[6]), 0.f);
        xr[7] = fmaxf(fmaf(a7, d, bf[7]), 0.f);
    }
    __syncthreads();

    // ---- phase 2: Xs[128,48] @ W2[48,32] -> Hh2 (fp16, pre-scaled) ----
    int tc = tid & 3, tr = tid >> 2;
    int r0l = 2 * tr, c0 = tc * 8;
    float acc[2][8];
#pragma unroll
    for (int rr = 0; rr < 2; ++rr)
#pragma unroll
        for (int j = 0; j < 8; ++j) acc[rr][j] = 0.f;
#pragma unroll 4
    for (int k = 0; k < 48; ++k) {
        float x0 = Xs[r0l * XS + k];
        float x1 = Xs[(r0l + 1) * XS + k];
        float4 wv0 = *(const float4*)&w2[k * 32 + c0];
        float4 wv1 = *(const float4*)&w2[k * 32 + c0 + 4];
        acc[0][0] = fmaf(x0, wv0.x, acc[0][0]); acc[0][1] = fmaf(x0, wv0.y, acc[0][1]);
        acc[0][2] = fmaf(x0, wv0.z, acc[0][2]); acc[0][3] = fmaf(x0, wv0.w, acc[0][3]);
        acc[0][4] = fmaf(x0, wv1.x, acc[0][4]); acc[0][5] = fmaf(x0, wv1.y, acc[0][5]);
        acc[0][6] = fmaf(x0, wv1.z, acc[0][6]); acc[0][7] = fmaf(x0, wv1.w, acc[0][7]);
        acc[1][0] = fmaf(x1, wv0.x, acc[1][0]); acc[1][1] = fmaf(x1, wv0.y, acc[1][1]);
        acc[1][2] = fmaf(x1, wv0.z, acc[1][2]); acc[1][3] = fmaf(x1, wv0.w, acc[1][3]);
        acc[1][4] = fmaf(x1, wv1.x, acc[1][4]); acc[1][5] = fmaf(x1, wv1.y, acc[1][5]);
        acc[1][6] = fmaf(x1, wv1.z, acc[1][6]); acc[1][7] = fmaf(x1, wv1.w, acc[1][7]);
    }
#pragma unroll
    for (int rr = 0; rr < 2; ++rr) {
        int gr = R0 + r0l + rr;
        if (gr >= NN) continue;
        float d = dinv[gr];
        __half2 p0 = __floats2half2_rn(acc[rr][0] * d, acc[rr][1] * d);
        __half2 p1 = __floats2half2_rn(acc[rr][2] * d, acc[rr][3] * d);
        __half2 p2 = __floats2half2_rn(acc[rr][4] * d, acc[rr][5] * d);
        __half2 p3 = __floats2half2_rn(acc[rr][6] * d, acc[rr][7] * d);
        half8 hv; hv.a = p0; hv.b = p1; hv.c = p2; hv.d = p3;
        *(half8*)(Hh2 + (size_t)gr * 32 + c0) = hv;
    }
}

// Layer-2 aggregation: out[i,:] = dinv[i]*(Hh2[i,:] + sum Hh2[src,:]) + b2
// (Hh2 rows pre-scaled by dinv[src] in fused48 phase 2.)
template <int NC>
__global__ void k_agg(const __half* __restrict__ Hh, const unsigned int* __restrict__ rowinfo,
                      const int* __restrict__ srcsort, const float* __restrict__ dinv,
                      const float* __restrict__ bias, float* __restrict__ out) {
    constexpr int Q = NC / 8;
    int idx = blockIdx.x * blockDim.x + threadIdx.x;
    if (idx >= NN * Q) return;
    int r = idx / Q, q = idx - r * Q;
    half8 sv = *(const half8*)(Hh + (size_t)r * NC + 8 * q);
    float2 f0 = __half22float2(sv.a), f1 = __half22float2(sv.b);
    float2 f2 = __half22float2(sv.c), f3 = __half22float2(sv.d);
    float a0 = f0.x, a1 = f0.y, a2 = f1.x, a3 = f1.y;
    float a4 = f2.x, a5 = f2.y, a6 = f3.x, a7 = f3.y;
    unsigned int rp = rowinfo[r];
    int e0 = rp >> 10, e1 = e0 + (int)(rp & 1023);
    for (int e = e0; e < e1; e += UN) {
        int ss[UN]; float ms[UN];
#pragma unroll
        for (int u = 0; u < UN; ++u) {
            int ee = e + u;
            bool ok = ee < e1;
            ss[u] = srcsort[ok ? ee : e0];
            ms[u] = ok ? 1.f : 0.f;
        }
        half8 vv[UN];
#pragma unroll
        for (int u = 0; u < UN; ++u)
            vv[u] = *(const half8*)(Hh + (size_t)ss[u] * NC + 8 * q);
#pragma unroll
        for (int u = 0; u < UN; ++u) {
            float2 g0 = __half22float2(vv[u].a), g1 = __half22float2(vv[u].b);
            float2 g2 = __half22float2(vv[u].c), g3 = __half22float2(vv[u].d);
            float m = ms[u];
            a0 = fmaf(g0.x, m, a0); a1 = fmaf(g0.y, m, a1);
            a2 = fmaf(g1.x, m, a2); a3 = fmaf(g1.y, m, a3);
            a4 = fmaf(g2.x, m, a4); a5 = fmaf(g2.y, m, a5);
            a6 = fmaf(g3.x, m, a6); a7 = fmaf(g3.y, m, a7);
        }
    }
    float d = dinv[r];
    const float4* b4 = (const float4*)bias;
    float4 bv0 = b4[2 * q], bv1 = b4[2 * q + 1];
    a0 = fmaf(a0, d, bv0.x); a1 = fmaf(a1, d, bv0.y);
    a2 = fmaf(a2, d, bv0.z); a3 = fmaf(a3, d, bv0.w);
    a4 = fmaf(a4, d, bv1.x); a5 = fmaf(a5, d, bv1.y);
    a6 = fmaf(a6, d, bv1.z); a7 = fmaf(a7, d, bv1.w);
    float4* o4 = (float4*)(out + (size_t)r * NC + 8 * q);
    o4[0] = make_float4(a0, a1, a2, a3);
    o4[1] = make_float4(a4, a5, a6, a7);
}

extern "C" void kernel_launch(void* const* d_in, const int* in_sizes, int n_in,
                              void* d_out, int out_size, void* d_ws, size_t ws_size,
                              hipStream_t stream) {
    const float* x  = (const float*)d_in[0];
    const int*   ei = (const int*)d_in[1];   // [2,NE] int32
    const float* W1 = (const float*)d_in[2];
    const float* b1 = (const float*)d_in[3];
    const float* W2 = (const float*)d_in[4];
    const float* b2 = (const float*)d_in[5];
    float* out = (float*)d_out;

    const int* src = ei;
    const int* dst = ei + NE;

    char* p = (char*)d_ws;
    auto take = [&](size_t elems) { void* q = p; p += ((elems * 4 + 255) & ~255ull); return q; };
    int*          cursor  = (int*)take(NBUCK);
    unsigned int* rowinfo = (unsigned int*)take(NN);
    float*        dinv    = (float*)take(NN);
    int*          srcsort = (int*)take((size_t)NBUCK * CAP);   // bucket-padded
    __half*       Hh      = (__half*)take((size_t)NN * 24);    // NN*48 halves
    int*          packed  = (int*)take((size_t)NBUCK * CAP);   // dead after bsort
    __half*       Hh2     = (__half*)packed;                   // reuse

    const int B = 256;
    const int GB = GEMMB;              // 782
    // --- fat: gemm1 (unscaled) || edge partition ---
    hipMemsetAsync(cursor, 0, NBUCK * sizeof(int), stream);
    k_fat<<<GEMMB + PARTB, 256, 0, stream>>>(x, W1, Hh, src, dst, cursor, packed);
    // --- per-bucket counting sort + rowinfo + dinv ---
    k_bsort<<<NBUCK, 256, 0, stream>>>(packed, cursor, srcsort, rowinfo, dinv);
    // --- fused: layer-1 aggregation (dinv in gather) + relu/b1 + GEMM2 ---
    k_fused48<<<GB, 256, 0, stream>>>(Hh, rowinfo, srcsort, dinv, b1, W2, Hh2);
    // --- layer-2 aggregation (+b2) ---
    k_agg<32><<<(NN * 4 + B - 1) / B, B, 0, stream>>>(Hh2, rowinfo, srcsort, dinv, b2, out);
}

// Round 17
// 210.057 us; speedup vs baseline: 1.0016x; 1.0016x over previous
//
#include <hip/hip_runtime.h>
#include <hip/hip_fp16.h>

// GCN 2-layer. Edges partitioned into 782 static dst-buckets (CAP=4096;
// Binom(1.6M,1/782): mean 2048, sd 45 -- overflow is 45-sigma), counting-
// sorted per bucket by (dst_local, src_chunk). rowinfo = (start<<10)|deg.
// fp16 features (r9), GEMM2 fused into layer-1 agg via LDS tile (r12,
// 128-row geometry), masked full-width gather batches (r15). r17: UN 8->16
// -- per-row latency scales with BATCH count (one waitcnt drain per batch);
// Poisson(16) degrees drop from ~2.3 to ~1.5 batches/row.
// r16 lesson: merging heterogeneous block types into one fat kernel unions
// LDS footprints and serializes anyway (58 us vs 27 us split) -- reverted.
// r15 lesson: the serial gather TAIL was the latency chain; masked batches fix.
// r13/r14 lesson: occupancy (grid- or wave-derived) is NOT the agg limiter.
// r11 lesson: gather width/count neutral -- agg is latency/fabric bound.
// r8 lesson: non-contiguous feature slicing explodes line traffic (1.13 GB).
// r5 lesson: transposed-X LDS staging + full unroll => scratch spill.
// out = GCNConv(relu(GCNConv(x,W1,b1)), W2, b2); N=100k, E=1.6M, 64->48->32.

#define NN 100000
#define NE 1600000
#define NPB 128                         // nodes per bucket
#define NBUCK ((NN + NPB - 1) / NPB)    // 782
#define PBITS 17                        // src fits in 17 bits
#define PMASK ((1 << PBITS) - 1)
#define CHB 3                           // log2 src chunks
#define CHS 14                          // chunk = src >> 14
#define NKEY (NPB << CHB)               // 1024 sort keys per bucket
#define PART_B 512
#define EPT 8                           // edges per thread (391 blocks)
#define PART_G ((NE + PART_B * EPT - 1) / (PART_B * EPT))   // 391
#define CAP 4096                        // static slots per bucket
#define UN 16                           // agg edge-loop unroll (masked batches)

struct alignas(8)  half4 { __half2 lo, hi; };
struct alignas(16) half8 { __half2 a, b, c, d; };

// partition edges into static bucket slots; packed = src | (dst_local<<PBITS)
__global__ void k_part(const int* __restrict__ src, const int* __restrict__ dst,
                       int* __restrict__ cursor, int* __restrict__ packed) {
    __shared__ int h[NBUCK];
    __shared__ int base[NBUCK];
    for (int i = threadIdx.x; i < NBUCK; i += blockDim.x) h[i] = 0;
    __syncthreads();
    int ebase = blockIdx.x * (PART_B * EPT);
    for (int k = 0; k < EPT; ++k) {
        int e = ebase + k * PART_B + threadIdx.x;
        if (e < NE) atomicAdd(&h[dst[e] >> 7], 1);
    }
    __syncthreads();
    for (int i = threadIdx.x; i < NBUCK; i += blockDim.x) {
        int c = h[i];
        if (c) base[i] = atomicAdd(&cursor[i], c);
        h[i] = 0;
    }
    __syncthreads();
    for (int k = 0; k < EPT; ++k) {
        int e = ebase + k * PART_B + threadIdx.x;
        if (e < NE) {
            int d = dst[e];
            int b = d >> 7;
            int r = atomicAdd(&h[b], 1);
            packed[(size_t)b * CAP + base[b] + r] = src[e] | ((d & (NPB - 1)) << PBITS);
        }
    }
}

// per-bucket counting sort by (dst_local, src_chunk) -> srcsort (bucket-padded),
// rowinfo = (global_start << 10) | deg, dinv = rsqrt(deg+1).
__global__ void k_bsort(const int* __restrict__ packed, const int* __restrict__ cursor,
                        int* __restrict__ srcsort, unsigned int* __restrict__ rowinfo,
                        float* __restrict__ dinv) {
    __shared__ int stage[CAP];          // 16 KB (sz <= CAP always)
    __shared__ int cnt[NKEY];           // 4 KB
    __shared__ int tsum[256];
    int tid = threadIdx.x, b = blockIdx.x;
    int e0 = b * CAP, sz = cursor[b];
    for (int i = tid; i < NKEY; i += 256) cnt[i] = 0;
    __syncthreads();
    for (int i = tid; i < sz; i += 256) {
        int w = packed[e0 + i];
        stage[i] = w;
        int key = ((w >> PBITS) << CHB) | ((w & PMASK) >> CHS);
        atomicAdd(&cnt[key], 1);
    }
    __syncthreads();
    int k0 = tid * 4;
    int c0 = cnt[k0], c1 = cnt[k0 + 1], c2 = cnt[k0 + 2], c3 = cnt[k0 + 3];
    int loc = c0 + c1 + c2 + c3;
    tsum[tid] = loc;
    __syncthreads();
    for (int off = 1; off < 256; off <<= 1) {
        int v = (tid >= off) ? tsum[tid - off] : 0;
        __syncthreads();
        tsum[tid] += v;
        __syncthreads();
    }
    int base = tsum[tid] - loc;
    cnt[k0]     = base;
    cnt[k0 + 1] = base + c0;
    cnt[k0 + 2] = base + c0 + c1;
    cnt[k0 + 3] = base + c0 + c1 + c2;
    __syncthreads();
    if (tid < NPB) {
        int node = b * NPB + tid;
        int rs = cnt[tid << CHB];
        int re = (tid == NPB - 1) ? sz : cnt[(tid + 1) << CHB];
        if (node < NN) {
            rowinfo[node] = ((unsigned int)(e0 + rs) << 10) | (unsigned int)(re - rs);
            dinv[node] = rsqrtf((float)(re - rs + 1));   // +1 self-loop
        }
    }
    __syncthreads();
    for (int i = tid; i < sz; i += 256) {
        int w = stage[i];
        int key = ((w >> PBITS) << CHB) | ((w & PMASK) >> CHS);
        int p = atomicAdd(&cnt[key], 1);
        srcsort[e0 + p] = w & PMASK;
    }
}

// Register-tiled GEMM1: Hh[M,48] = half( X[M,64] @ W1 * dinv[row] )
template <int K, int NC, int CPT>
__global__ __launch_bounds__(256) void
k_gemm(const float* __restrict__ X, const float* __restrict__ W,
       const float* __restrict__ dinv, __half* __restrict__ Hh, int M) {
    constexpr int CG = NC / CPT;
    constexpr int MT = (256 / CG) * 2;   // 128 rows per block
    constexpr int KF4 = K / 4;
    __shared__ float w[K * NC];
    int tid = threadIdx.x;
    int R0 = blockIdx.x * MT;
    for (int i = tid; i < K * NC; i += 256) w[i] = W[i];
    __syncthreads();

    int tc = tid % CG, tr = tid / CG;
    int r0 = R0 + 2 * tr, r1 = r0 + 1;
    int c0 = tc * CPT;
    bool ok0 = r0 < M, ok1 = r1 < M;
    const float4* X4 = (const float4*)X;
    const float4 z4 = make_float4(0.f, 0.f, 0.f, 0.f);

    float acc[2][CPT];
#pragma unroll
    for (int rr = 0; rr < 2; ++rr)
#pragma unroll
        for (int j = 0; j < CPT; ++j) acc[rr][j] = 0.f;

#pragma unroll 2
    for (int k4 = 0; k4 < KF4; ++k4) {
        float4 xa = ok0 ? X4[(size_t)r0 * KF4 + k4] : z4;
        float4 xb = ok1 ? X4[(size_t)r1 * KF4 + k4] : z4;
        float ar[4] = {xa.x, xa.y, xa.z, xa.w};
        float br[4] = {xb.x, xb.y, xb.z, xb.w};
#pragma unroll
        for (int j = 0; j < 4; ++j) {
            float va = ar[j], vb = br[j];
#pragma unroll
            for (int q = 0; q < CPT / 4; ++q) {
                float4 wv = *(const float4*)&w[(4 * k4 + j) * NC + c0 + 4 * q];
                acc[0][q*4+0] = fmaf(va, wv.x, acc[0][q*4+0]);
                acc[0][q*4+1] = fmaf(va, wv.y, acc[0][q*4+1]);
                acc[0][q*4+2] = fmaf(va, wv.z, acc[0][q*4+2]);
                acc[0][q*4+3] = fmaf(va, wv.w, acc[0][q*4+3]);
                acc[1][q*4+0] = fmaf(vb, wv.x, acc[1][q*4+0]);
                acc[1][q*4+1] = fmaf(vb, wv.y, acc[1][q*4+1]);
                acc[1][q*4+2] = fmaf(vb, wv.z, acc[1][q*4+2]);
                acc[1][q*4+3] = fmaf(vb, wv.w, acc[1][q*4+3]);
            }
        }
    }
#pragma unroll
    for (int rr = 0; rr < 2; ++rr) {
        int gr = r0 + rr;
        if (gr >= M) continue;
        float d = dinv[gr];
#pragma unroll
        for (int q = 0; q < CPT / 4; ++q) {
            __half2 p0 = __floats2half2_rn(acc[rr][q*4+0] * d, acc[rr][q*4+1] * d);
            __half2 p1 = __floats2half2_rn(acc[rr][q*4+2] * d, acc[rr][q*4+3] * d);
            half4 hv; hv.lo = p0; hv.hi = p1;
            *(half4*)(Hh + (size_t)gr * NC + c0 + 4 * q) = hv;
        }
    }
}

// Fused layer-1 aggregation + relu/b1 + GEMM2 + dinv. 128-row tile, 256 thr
// (r12 geometry). Masked full-width UN-batches: all gathers independent,
// no serial tail (lanes past deg clamp to srcsort[e0], mask 0 via fmaf).
__global__ __launch_bounds__(256) void
k_fused48(const __half* __restrict__ Hh, const unsigned int* __restrict__ rowinfo,
          const int* __restrict__ srcsort, const float* __restrict__ dinv,
          const float* __restrict__ b1, const float* __restrict__ W2,
          __half* __restrict__ Hh2) {
    constexpr int ROWS = 128, XS = 49;
    __shared__ float Xs[ROWS * XS];      // 25088 B
    __shared__ float w2[48 * 32];        // 6144 B
    __shared__ float bb[48];
    int tid = threadIdx.x;
    int R0 = blockIdx.x * ROWS;
    for (int i = tid; i < 48 * 32; i += 256) w2[i] = W2[i];
    if (tid < 48) bb[tid] = b1[tid];
    __syncthreads();

    // ---- phase 1: aggregate into Xs (3 (row,chunk) items per thread) ----
    for (int t = tid; t < ROWS * 6; t += 256) {
        int lr = t / 6, q = t - lr * 6;
        int r = R0 + lr;
        if (r >= NN) continue;
        half8 sv = *(const half8*)(Hh + (size_t)r * 48 + 8 * q);   // self-loop
        float2 f0 = __half22float2(sv.a), f1 = __half22float2(sv.b);
        float2 f2 = __half22float2(sv.c), f3 = __half22float2(sv.d);
        float a0 = f0.x, a1 = f0.y, a2 = f1.x, a3 = f1.y;
        float a4 = f2.x, a5 = f2.y, a6 = f3.x, a7 = f3.y;
        unsigned int rp = rowinfo[r];
        int e0 = rp >> 10, e1 = e0 + (int)(rp & 1023);
        for (int e = e0; e < e1; e += UN) {
            int ss[UN]; float ms[UN];
#pragma unroll
            for (int u = 0; u < UN; ++u) {
                int ee = e + u;
                bool ok = ee < e1;
                ss[u] = srcsort[ok ? ee : e0];
                ms[u] = ok ? 1.f : 0.f;
            }
            half8 vv[UN];
#pragma unroll
            for (int u = 0; u < UN; ++u)
                vv[u] = *(const half8*)(Hh + (size_t)ss[u] * 48 + 8 * q);
#pragma unroll
            for (int u = 0; u < UN; ++u) {
                float2 g0 = __half22float2(vv[u].a), g1 = __half22float2(vv[u].b);
                float2 g2 = __half22float2(vv[u].c), g3 = __half22float2(vv[u].d);
                float m = ms[u];
                a0 = fmaf(g0.x, m, a0); a1 = fmaf(g0.y, m, a1);
                a2 = fmaf(g1.x, m, a2); a3 = fmaf(g1.y, m, a3);
                a4 = fmaf(g2.x, m, a4); a5 = fmaf(g2.y, m, a5);
                a6 = fmaf(g3.x, m, a6); a7 = fmaf(g3.y, m, a7);
            }
        }
        float d = dinv[r];
        float* xr = &Xs[lr * XS + 8 * q];
        const float* bf = &bb[8 * q];
        xr[0] = fmaxf(fmaf(a0, d, bf[0]), 0.f);
        xr[1] = fmaxf(fmaf(a1, d, bf[1]), 0.f);
        xr[2] = fmaxf(fmaf(a2, d, bf[2]), 0.f);
        xr[3] = fmaxf(fmaf(a3, d, bf[3]), 0.f);
        xr[4] = fmaxf(fmaf(a4, d, bf[4]), 0.f);
        xr[5] = fmaxf(fmaf(a5, d, bf[5]), 0.f);
        xr[6] = fmaxf(fmaf(a6, d, bf[6]), 0.f);
        xr[7] = fmaxf(fmaf(a7, d, bf[7]), 0.f);
    }
    __syncthreads();

    // ---- phase 2: Xs[128,48] @ W2[48,32] -> Hh2 (fp16); 2 rows x 8 cols ----
    int tc = tid & 3, tr = tid >> 2;
    int r0l = 2 * tr, c0 = tc * 8;
    float acc[2][8];
#pragma unroll
    for (int rr = 0; rr < 2; ++rr)
#pragma unroll
        for (int j = 0; j < 8; ++j) acc[rr][j] = 0.f;
#pragma unroll 4
    for (int k = 0; k < 48; ++k) {
        float x0 = Xs[r0l * XS + k];
        float x1 = Xs[(r0l + 1) * XS + k];
        float4 wv0 = *(const float4*)&w2[k * 32 + c0];
        float4 wv1 = *(const float4*)&w2[k * 32 + c0 + 4];
        acc[0][0] = fmaf(x0, wv0.x, acc[0][0]); acc[0][1] = fmaf(x0, wv0.y, acc[0][1]);
        acc[0][2] = fmaf(x0, wv0.z, acc[0][2]); acc[0][3] = fmaf(x0, wv0.w, acc[0][3]);
        acc[0][4] = fmaf(x0, wv1.x, acc[0][4]); acc[0][5] = fmaf(x0, wv1.y, acc[0][5]);
        acc[0][6] = fmaf(x0, wv1.z, acc[0][6]); acc[0][7] = fmaf(x0, wv1.w, acc[0][7]);
        acc[1][0] = fmaf(x1, wv0.x, acc[1][0]); acc[1][1] = fmaf(x1, wv0.y, acc[1][1]);
        acc[1][2] = fmaf(x1, wv0.z, acc[1][2]); acc[1][3] = fmaf(x1, wv0.w, acc[1][3]);
        acc[1][4] = fmaf(x1, wv1.x, acc[1][4]); acc[1][5] = fmaf(x1, wv1.y, acc[1][5]);
        acc[1][6] = fmaf(x1, wv1.z, acc[1][6]); acc[1][7] = fmaf(x1, wv1.w, acc[1][7]);
    }
#pragma unroll
    for (int rr = 0; rr < 2; ++rr) {
        int gr = R0 + r0l + rr;
        if (gr >= NN) continue;
        float d = dinv[gr];
        __half2 p0 = __floats2half2_rn(acc[rr][0] * d, acc[rr][1] * d);
        __half2 p1 = __floats2half2_rn(acc[rr][2] * d, acc[rr][3] * d);
        __half2 p2 = __floats2half2_rn(acc[rr][4] * d, acc[rr][5] * d);
        __half2 p3 = __floats2half2_rn(acc[rr][6] * d, acc[rr][7] * d);
        half8 hv; hv.a = p0; hv.b = p1; hv.c = p2; hv.d = p3;
        *(half8*)(Hh2 + (size_t)gr * 32 + c0) = hv;
    }
}

// Layer-2 aggregation: out[i,:] = dinv[i]*(Hh2[i,:] + sum Hh2[src,:]) + b2
// Masked full-width UN-batches (no serial tail).
template <int NC>
__global__ void k_agg(const __half* __restrict__ Hh, const unsigned int* __restrict__ rowinfo,
                      const int* __restrict__ srcsort, const float* __restrict__ dinv,
                      const float* __restrict__ bias, float* __restrict__ out) {
    constexpr int Q = NC / 8;
    int idx = blockIdx.x * blockDim.x + threadIdx.x;
    if (idx >= NN * Q) return;
    int r = idx / Q, q = idx - r * Q;
    half8 sv = *(const half8*)(Hh + (size_t)r * NC + 8 * q);
    float2 f0 = __half22float2(sv.a), f1 = __half22float2(sv.b);
    float2 f2 = __half22float2(sv.c), f3 = __half22float2(sv.d);
    float a0 = f0.x, a1 = f0.y, a2 = f1.x, a3 = f1.y;
    float a4 = f2.x, a5 = f2.y, a6 = f3.x, a7 = f3.y;
    unsigned int rp = rowinfo[r];
    int e0 = rp >> 10, e1 = e0 + (int)(rp & 1023);
    for (int e = e0; e < e1; e += UN) {
        int ss[UN]; float ms[UN];
#pragma unroll
        for (int u = 0; u < UN; ++u) {
            int ee = e + u;
            bool ok = ee < e1;
            ss[u] = srcsort[ok ? ee : e0];
            ms[u] = ok ? 1.f : 0.f;
        }
        half8 vv[UN];
#pragma unroll
        for (int u = 0; u < UN; ++u)
            vv[u] = *(const half8*)(Hh + (size_t)ss[u] * NC + 8 * q);
#pragma unroll
        for (int u = 0; u < UN; ++u) {
            float2 g0 = __half22float2(vv[u].a), g1 = __half22float2(vv[u].b);
            float2 g2 = __half22float2(vv[u].c), g3 = __half22float2(vv[u].d);
            float m = ms[u];
            a0 = fmaf(g0.x, m, a0); a1 = fmaf(g0.y, m, a1);
            a2 = fmaf(g1.x, m, a2); a3 = fmaf(g1.y, m, a3);
            a4 = fmaf(g2.x, m, a4); a5 = fmaf(g2.y, m, a5);
            a6 = fmaf(g3.x, m, a6); a7 = fmaf(g3.y, m, a7);
        }
    }
    float d = dinv[r];
    const float4* b4 = (const float4*)bias;
    float4 bv0 = b4[2 * q], bv1 = b4[2 * q + 1];
    a0 = fmaf(a0, d, bv0.x); a1 = fmaf(a1, d, bv0.y);
    a2 = fmaf(a2, d, bv0.z); a3 = fmaf(a3, d, bv0.w);
    a4 = fmaf(a4, d, bv1.x); a5 = fmaf(a5, d, bv1.y);
    a6 = fmaf(a6, d, bv1.z); a7 = fmaf(a7, d, bv1.w);
    float4* o4 = (float4*)(out + (size_t)r * NC + 8 * q);
    o4[0] = make_float4(a0, a1, a2, a3);
    o4[1] = make_float4(a4, a5, a6, a7);
}

extern "C" void kernel_launch(void* const* d_in, const int* in_sizes, int n_in,
                              void* d_out, int out_size, void* d_ws, size_t ws_size,
                              hipStream_t stream) {
    const float* x  = (const float*)d_in[0];
    const int*   ei = (const int*)d_in[1];   // [2,NE] int32
    const float* W1 = (const float*)d_in[2];
    const float* b1 = (const float*)d_in[3];
    const float* W2 = (const float*)d_in[4];
    const float* b2 = (const float*)d_in[5];
    float* out = (float*)d_out;

    const int* src = ei;
    const int* dst = ei + NE;

    char* p = (char*)d_ws;
    auto take = [&](size_t elems) { void* q = p; p += ((elems * 4 + 255) & ~255ull); return q; };
    int*          cursor  = (int*)take(NBUCK);
    unsigned int* rowinfo = (unsigned int*)take(NN);
    float*        dinv    = (float*)take(NN);
    int*          srcsort = (int*)take((size_t)NBUCK * CAP);   // bucket-padded
    __half*       Hh      = (__half*)take((size_t)NN * 24);    // NN*48 halves
    int*          packed  = (int*)take((size_t)NBUCK * CAP);   // dead after bsort
    __half*       Hh2     = (__half*)packed;                   // reuse

    const int B = 256;
    const int GB = (NN + 127) / 128;   // 782 blocks
    // --- dst-sort of edges (static bucket slots) ---
    hipMemsetAsync(cursor, 0, NBUCK * sizeof(int), stream);
    k_part<<<PART_G, PART_B, 0, stream>>>(src, dst, cursor, packed);
    k_bsort<<<NBUCK, 256, 0, stream>>>(packed, cursor, srcsort, rowinfo, dinv);

    // --- layer 1 transform ---
    k_gemm<64, 48, 12><<<GB, 256, 0, stream>>>(x, W1, dinv, Hh, NN);
    // --- fused: layer-1 aggregation + relu/b1 + GEMM2 + dinv ---
    k_fused48<<<GB, 256, 0, stream>>>(Hh, rowinfo, srcsort, dinv, b1, W2, Hh2);
    // --- layer-2 aggregation (+b2) ---
    k_agg<32><<<(NN * 4 + B - 1) / B, B, 0, stream>>>(Hh2, rowinfo, srcsort, dinv, b2, out);
}

// Round 18
// 206.628 us; speedup vs baseline: 1.0182x; 1.0166x over previous
//
#include <hip/hip_runtime.h>
#include <hip/hip_fp16.h>

// GCN 2-layer -- FINAL (r15 configuration, best measured: 207.5 us).
// Edges partitioned into 782 static dst-buckets (CAP=4096; Binom(1.6M,1/782):
// mean 2048, sd 45 -- overflow is 45-sigma), counting-sorted per bucket by
// (dst_local, src_chunk). rowinfo = (start<<10)|deg. fp16 features (r9),
// GEMM2 fused into layer-1 agg via LDS tile (r12, 128-row geometry), masked
// full-width UN=8 gather batches (r15 -- kills the serial gather tail).
// Ceiling: both aggregation passes run compulsory traffic (8 XCDs x full
// feature array; per-XCD L2s not cross-coherent) at the measured ~2.4-3 TB/s
// random-line fabric ceiling. Proven-neutral/negative levers: gather width
// (r11), occupancy 23->57% (r13/r14), batch count UN=16 (r17), XCD feature
// slicing (r8: 1.13 GB line explosion), fat-kernel merge (r16: LDS union,
// no overlap), fp8 would blow the 7.7e-3 absmax threshold.
// out = GCNConv(relu(GCNConv(x,W1,b1)), W2, b2); N=100k, E=1.6M, 64->48->32.

#define NN 100000
#define NE 1600000
#define NPB 128                         // nodes per bucket
#define NBUCK ((NN + NPB - 1) / NPB)    // 782
#define PBITS 17                        // src fits in 17 bits
#define PMASK ((1 << PBITS) - 1)
#define CHB 3                           // log2 src chunks
#define CHS 14                          // chunk = src >> 14
#define NKEY (NPB << CHB)               // 1024 sort keys per bucket
#define PART_B 512
#define EPT 8                           // edges per thread (391 blocks)
#define PART_G ((NE + PART_B * EPT - 1) / (PART_B * EPT))   // 391
#define CAP 4096                        // static slots per bucket
#define UN 8                            // agg edge-loop unroll (masked batches)

struct alignas(8)  half4 { __half2 lo, hi; };
struct alignas(16) half8 { __half2 a, b, c, d; };

// partition edges into static bucket slots; packed = src | (dst_local<<PBITS)
__global__ void k_part(const int* __restrict__ src, const int* __restrict__ dst,
                       int* __restrict__ cursor, int* __restrict__ packed) {
    __shared__ int h[NBUCK];
    __shared__ int base[NBUCK];
    for (int i = threadIdx.x; i < NBUCK; i += blockDim.x) h[i] = 0;
    __syncthreads();
    int ebase = blockIdx.x * (PART_B * EPT);
    for (int k = 0; k < EPT; ++k) {
        int e = ebase + k * PART_B + threadIdx.x;
        if (e < NE) atomicAdd(&h[dst[e] >> 7], 1);
    }
    __syncthreads();
    for (int i = threadIdx.x; i < NBUCK; i += blockDim.x) {
        int c = h[i];
        if (c) base[i] = atomicAdd(&cursor[i], c);
        h[i] = 0;
    }
    __syncthreads();
    for (int k = 0; k < EPT; ++k) {
        int e = ebase + k * PART_B + threadIdx.x;
        if (e < NE) {
            int d = dst[e];
            int b = d >> 7;
            int r = atomicAdd(&h[b], 1);
            packed[(size_t)b * CAP + base[b] + r] = src[e] | ((d & (NPB - 1)) << PBITS);
        }
    }
}

// per-bucket counting sort by (dst_local, src_chunk) -> srcsort (bucket-padded),
// rowinfo = (global_start << 10) | deg, dinv = rsqrt(deg+1).
__global__ void k_bsort(const int* __restrict__ packed, const int* __restrict__ cursor,
                        int* __restrict__ srcsort, unsigned int* __restrict__ rowinfo,
                        float* __restrict__ dinv) {
    __shared__ int stage[CAP];          // 16 KB (sz <= CAP always)
    __shared__ int cnt[NKEY];           // 4 KB
    __shared__ int tsum[256];
    int tid = threadIdx.x, b = blockIdx.x;
    int e0 = b * CAP, sz = cursor[b];
    for (int i = tid; i < NKEY; i += 256) cnt[i] = 0;
    __syncthreads();
    for (int i = tid; i < sz; i += 256) {
        int w = packed[e0 + i];
        stage[i] = w;
        int key = ((w >> PBITS) << CHB) | ((w & PMASK) >> CHS);
        atomicAdd(&cnt[key], 1);
    }
    __syncthreads();
    int k0 = tid * 4;
    int c0 = cnt[k0], c1 = cnt[k0 + 1], c2 = cnt[k0 + 2], c3 = cnt[k0 + 3];
    int loc = c0 + c1 + c2 + c3;
    tsum[tid] = loc;
    __syncthreads();
    for (int off = 1; off < 256; off <<= 1) {
        int v = (tid >= off) ? tsum[tid - off] : 0;
        __syncthreads();
        tsum[tid] += v;
        __syncthreads();
    }
    int base = tsum[tid] - loc;
    cnt[k0]     = base;
    cnt[k0 + 1] = base + c0;
    cnt[k0 + 2] = base + c0 + c1;
    cnt[k0 + 3] = base + c0 + c1 + c2;
    __syncthreads();
    if (tid < NPB) {
        int node = b * NPB + tid;
        int rs = cnt[tid << CHB];
        int re = (tid == NPB - 1) ? sz : cnt[(tid + 1) << CHB];
        if (node < NN) {
            rowinfo[node] = ((unsigned int)(e0 + rs) << 10) | (unsigned int)(re - rs);
            dinv[node] = rsqrtf((float)(re - rs + 1));   // +1 self-loop
        }
    }
    __syncthreads();
    for (int i = tid; i < sz; i += 256) {
        int w = stage[i];
        int key = ((w >> PBITS) << CHB) | ((w & PMASK) >> CHS);
        int p = atomicAdd(&cnt[key], 1);
        srcsort[e0 + p] = w & PMASK;
    }
}

// Register-tiled GEMM1: Hh[M,48] = half( X[M,64] @ W1 * dinv[row] )
template <int K, int NC, int CPT>
__global__ __launch_bounds__(256) void
k_gemm(const float* __restrict__ X, const float* __restrict__ W,
       const float* __restrict__ dinv, __half* __restrict__ Hh, int M) {
    constexpr int CG = NC / CPT;
    constexpr int MT = (256 / CG) * 2;   // 128 rows per block
    constexpr int KF4 = K / 4;
    __shared__ float w[K * NC];
    int tid = threadIdx.x;
    int R0 = blockIdx.x * MT;
    for (int i = tid; i < K * NC; i += 256) w[i] = W[i];
    __syncthreads();

    int tc = tid % CG, tr = tid / CG;
    int r0 = R0 + 2 * tr, r1 = r0 + 1;
    int c0 = tc * CPT;
    bool ok0 = r0 < M, ok1 = r1 < M;
    const float4* X4 = (const float4*)X;
    const float4 z4 = make_float4(0.f, 0.f, 0.f, 0.f);

    float acc[2][CPT];
#pragma unroll
    for (int rr = 0; rr < 2; ++rr)
#pragma unroll
        for (int j = 0; j < CPT; ++j) acc[rr][j] = 0.f;

#pragma unroll 2
    for (int k4 = 0; k4 < KF4; ++k4) {
        float4 xa = ok0 ? X4[(size_t)r0 * KF4 + k4] : z4;
        float4 xb = ok1 ? X4[(size_t)r1 * KF4 + k4] : z4;
        float ar[4] = {xa.x, xa.y, xa.z, xa.w};
        float br[4] = {xb.x, xb.y, xb.z, xb.w};
#pragma unroll
        for (int j = 0; j < 4; ++j) {
            float va = ar[j], vb = br[j];
#pragma unroll
            for (int q = 0; q < CPT / 4; ++q) {
                float4 wv = *(const float4*)&w[(4 * k4 + j) * NC + c0 + 4 * q];
                acc[0][q*4+0] = fmaf(va, wv.x, acc[0][q*4+0]);
                acc[0][q*4+1] = fmaf(va, wv.y, acc[0][q*4+1]);
                acc[0][q*4+2] = fmaf(va, wv.z, acc[0][q*4+2]);
                acc[0][q*4+3] = fmaf(va, wv.w, acc[0][q*4+3]);
                acc[1][q*4+0] = fmaf(vb, wv.x, acc[1][q*4+0]);
                acc[1][q*4+1] = fmaf(vb, wv.y, acc[1][q*4+1]);
                acc[1][q*4+2] = fmaf(vb, wv.z, acc[1][q*4+2]);
                acc[1][q*4+3] = fmaf(vb, wv.w, acc[1][q*4+3]);
            }
        }
    }
#pragma unroll
    for (int rr = 0; rr < 2; ++rr) {
        int gr = r0 + rr;
        if (gr >= M) continue;
        float d = dinv[gr];
#pragma unroll
        for (int q = 0; q < CPT / 4; ++q) {
            __half2 p0 = __floats2half2_rn(acc[rr][q*4+0] * d, acc[rr][q*4+1] * d);
            __half2 p1 = __floats2half2_rn(acc[rr][q*4+2] * d, acc[rr][q*4+3] * d);
            half4 hv; hv.lo = p0; hv.hi = p1;
            *(half4*)(Hh + (size_t)gr * NC + c0 + 4 * q) = hv;
        }
    }
}

// Fused layer-1 aggregation + relu/b1 + GEMM2 + dinv. 128-row tile, 256 thr
// (r12 geometry). Masked full-width UN-batches: all gathers independent,
// no serial tail (lanes past deg clamp to srcsort[e0], mask 0 via fmaf).
__global__ __launch_bounds__(256) void
k_fused48(const __half* __restrict__ Hh, const unsigned int* __restrict__ rowinfo,
          const int* __restrict__ srcsort, const float* __restrict__ dinv,
          const float* __restrict__ b1, const float* __restrict__ W2,
          __half* __restrict__ Hh2) {
    constexpr int ROWS = 128, XS = 49;
    __shared__ float Xs[ROWS * XS];      // 25088 B
    __shared__ float w2[48 * 32];        // 6144 B
    __shared__ float bb[48];
    int tid = threadIdx.x;
    int R0 = blockIdx.x * ROWS;
    for (int i = tid; i < 48 * 32; i += 256) w2[i] = W2[i];
    if (tid < 48) bb[tid] = b1[tid];
    __syncthreads();

    // ---- phase 1: aggregate into Xs (3 (row,chunk) items per thread) ----
    for (int t = tid; t < ROWS * 6; t += 256) {
        int lr = t / 6, q = t - lr * 6;
        int r = R0 + lr;
        if (r >= NN) continue;
        half8 sv = *(const half8*)(Hh + (size_t)r * 48 + 8 * q);   // self-loop
        float2 f0 = __half22float2(sv.a), f1 = __half22float2(sv.b);
        float2 f2 = __half22float2(sv.c), f3 = __half22float2(sv.d);
        float a0 = f0.x, a1 = f0.y, a2 = f1.x, a3 = f1.y;
        float a4 = f2.x, a5 = f2.y, a6 = f3.x, a7 = f3.y;
        unsigned int rp = rowinfo[r];
        int e0 = rp >> 10, e1 = e0 + (int)(rp & 1023);
        for (int e = e0; e < e1; e += UN) {
            int ss[UN]; float ms[UN];
#pragma unroll
            for (int u = 0; u < UN; ++u) {
                int ee = e + u;
                bool ok = ee < e1;
                ss[u] = srcsort[ok ? ee : e0];
                ms[u] = ok ? 1.f : 0.f;
            }
            half8 vv[UN];
#pragma unroll
            for (int u = 0; u < UN; ++u)
                vv[u] = *(const half8*)(Hh + (size_t)ss[u] * 48 + 8 * q);
#pragma unroll
            for (int u = 0; u < UN; ++u) {
                float2 g0 = __half22float2(vv[u].a), g1 = __half22float2(vv[u].b);
                float2 g2 = __half22float2(vv[u].c), g3 = __half22float2(vv[u].d);
                float m = ms[u];
                a0 = fmaf(g0.x, m, a0); a1 = fmaf(g0.y, m, a1);
                a2 = fmaf(g1.x, m, a2); a3 = fmaf(g1.y, m, a3);
                a4 = fmaf(g2.x, m, a4); a5 = fmaf(g2.y, m, a5);
                a6 = fmaf(g3.x, m, a6); a7 = fmaf(g3.y, m, a7);
            }
        }
        float d = dinv[r];
        float* xr = &Xs[lr * XS + 8 * q];
        const float* bf = &bb[8 * q];
        xr[0] = fmaxf(fmaf(a0, d, bf[0]), 0.f);
        xr[1] = fmaxf(fmaf(a1, d, bf[1]), 0.f);
        xr[2] = fmaxf(fmaf(a2, d, bf[2]), 0.f);
        xr[3] = fmaxf(fmaf(a3, d, bf[3]), 0.f);
        xr[4] = fmaxf(fmaf(a4, d, bf[4]), 0.f);
        xr[5] = fmaxf(fmaf(a5, d, bf[5]), 0.f);
        xr[6] = fmaxf(fmaf(a6, d, bf[6]), 0.f);
        xr[7] = fmaxf(fmaf(a7, d, bf[7]), 0.f);
    }
    __syncthreads();

    // ---- phase 2: Xs[128,48] @ W2[48,32] -> Hh2 (fp16); 2 rows x 8 cols ----
    int tc = tid & 3, tr = tid >> 2;
    int r0l = 2 * tr, c0 = tc * 8;
    float acc[2][8];
#pragma unroll
    for (int rr = 0; rr < 2; ++rr)
#pragma unroll
        for (int j = 0; j < 8; ++j) acc[rr][j] = 0.f;
#pragma unroll 4
    for (int k = 0; k < 48; ++k) {
        float x0 = Xs[r0l * XS + k];
        float x1 = Xs[(r0l + 1) * XS + k];
        float4 wv0 = *(const float4*)&w2[k * 32 + c0];
        float4 wv1 = *(const float4*)&w2[k * 32 + c0 + 4];
        acc[0][0] = fmaf(x0, wv0.x, acc[0][0]); acc[0][1] = fmaf(x0, wv0.y, acc[0][1]);
        acc[0][2] = fmaf(x0, wv0.z, acc[0][2]); acc[0][3] = fmaf(x0, wv0.w, acc[0][3]);
        acc[0][4] = fmaf(x0, wv1.x, acc[0][4]); acc[0][5] = fmaf(x0, wv1.y, acc[0][5]);
        acc[0][6] = fmaf(x0, wv1.z, acc[0][6]); acc[0][7] = fmaf(x0, wv1.w, acc[0][7]);
        acc[1][0] = fmaf(x1, wv0.x, acc[1][0]); acc[1][1] = fmaf(x1, wv0.y, acc[1][1]);
        acc[1][2] = fmaf(x1, wv0.z, acc[1][2]); acc[1][3] = fmaf(x1, wv0.w, acc[1][3]);
        acc[1][4] = fmaf(x1, wv1.x, acc[1][4]); acc[1][5] = fmaf(x1, wv1.y, acc[1][5]);
        acc[1][6] = fmaf(x1, wv1.z, acc[1][6]); acc[1][7] = fmaf(x1, wv1.w, acc[1][7]);
    }
#pragma unroll
    for (int rr = 0; rr < 2; ++rr) {
        int gr = R0 + r0l + rr;
        if (gr >= NN) continue;
        float d = dinv[gr];
        __half2 p0 = __floats2half2_rn(acc[rr][0] * d, acc[rr][1] * d);
        __half2 p1 = __floats2half2_rn(acc[rr][2] * d, acc[rr][3] * d);
        __half2 p2 = __floats2half2_rn(acc[rr][4] * d, acc[rr][5] * d);
        __half2 p3 = __floats2half2_rn(acc[rr][6] * d, acc[rr][7] * d);
        half8 hv; hv.a = p0; hv.b = p1; hv.c = p2; hv.d = p3;
        *(half8*)(Hh2 + (size_t)gr * 32 + c0) = hv;
    }
}

// Layer-2 aggregation: out[i,:] = dinv[i]*(Hh2[i,:] + sum Hh2[src,:]) + b2
// Masked full-width UN-batches (no serial tail).
template <int NC>
__global__ void k_agg(const __half* __restrict__ Hh, const unsigned int* __restrict__ rowinfo,
                      const int* __restrict__ srcsort, const float* __restrict__ dinv,
                      const float* __restrict__ bias, float* __restrict__ out) {
    constexpr int Q = NC / 8;
    int idx = blockIdx.x * blockDim.x + threadIdx.x;
    if (idx >= NN * Q) return;
    int r = idx / Q, q = idx - r * Q;
    half8 sv = *(const half8*)(Hh + (size_t)r * NC + 8 * q);
    float2 f0 = __half22float2(sv.a), f1 = __half22float2(sv.b);
    float2 f2 = __half22float2(sv.c), f3 = __half22float2(sv.d);
    float a0 = f0.x, a1 = f0.y, a2 = f1.x, a3 = f1.y;
    float a4 = f2.x, a5 = f2.y, a6 = f3.x, a7 = f3.y;
    unsigned int rp = rowinfo[r];
    int e0 = rp >> 10, e1 = e0 + (int)(rp & 1023);
    for (int e = e0; e < e1; e += UN) {
        int ss[UN]; float ms[UN];
#pragma unroll
        for (int u = 0; u < UN; ++u) {
            int ee = e + u;
            bool ok = ee < e1;
            ss[u] = srcsort[ok ? ee : e0];
            ms[u] = ok ? 1.f : 0.f;
        }
        half8 vv[UN];
#pragma unroll
        for (int u = 0; u < UN; ++u)
            vv[u] = *(const half8*)(Hh + (size_t)ss[u] * NC + 8 * q);
#pragma unroll
        for (int u = 0; u < UN; ++u) {
            float2 g0 = __half22float2(vv[u].a), g1 = __half22float2(vv[u].b);
            float2 g2 = __half22float2(vv[u].c), g3 = __half22float2(vv[u].d);
            float m = ms[u];
            a0 = fmaf(g0.x, m, a0); a1 = fmaf(g0.y, m, a1);
            a2 = fmaf(g1.x, m, a2); a3 = fmaf(g1.y, m, a3);
            a4 = fmaf(g2.x, m, a4); a5 = fmaf(g2.y, m, a5);
            a6 = fmaf(g3.x, m, a6); a7 = fmaf(g3.y, m, a7);
        }
    }
    float d = dinv[r];
    const float4* b4 = (const float4*)bias;
    float4 bv0 = b4[2 * q], bv1 = b4[2 * q + 1];
    a0 = fmaf(a0, d, bv0.x); a1 = fmaf(a1, d, bv0.y);
    a2 = fmaf(a2, d, bv0.z); a3 = fmaf(a3, d, bv0.w);
    a4 = fmaf(a4, d, bv1.x); a5 = fmaf(a5, d, bv1.y);
    a6 = fmaf(a6, d, bv1.z); a7 = fmaf(a7, d, bv1.w);
    float4* o4 = (float4*)(out + (size_t)r * NC + 8 * q);
    o4[0] = make_float4(a0, a1, a2, a3);
    o4[1] = make_float4(a4, a5, a6, a7);
}

extern "C" void kernel_launch(void* const* d_in, const int* in_sizes, int n_in,
                              void* d_out, int out_size, void* d_ws, size_t ws_size,
                              hipStream_t stream) {
    const float* x  = (const float*)d_in[0];
    const int*   ei = (const int*)d_in[1];   // [2,NE] int32
    const float* W1 = (const float*)d_in[2];
    const float* b1 = (const float*)d_in[3];
    const float* W2 = (const float*)d_in[4];
    const float* b2 = (const float*)d_in[5];
    float* out = (float*)d_out;

    const int* src = ei;
    const int* dst = ei + NE;

    char* p = (char*)d_ws;
    auto take = [&](size_t elems) { void* q = p; p += ((elems * 4 + 255) & ~255ull); return q; };
    int*          cursor  = (int*)take(NBUCK);
    unsigned int* rowinfo = (unsigned int*)take(NN);
    float*        dinv    = (float*)take(NN);
    int*          srcsort = (int*)take((size_t)NBUCK * CAP);   // bucket-padded
    __half*       Hh      = (__half*)take((size_t)NN * 24);    // NN*48 halves
    int*          packed  = (int*)take((size_t)NBUCK * CAP);   // dead after bsort
    __half*       Hh2     = (__half*)packed;                   // reuse

    const int B = 256;
    const int GB = (NN + 127) / 128;   // 782 blocks
    // --- dst-sort of edges (static bucket slots) ---
    hipMemsetAsync(cursor, 0, NBUCK * sizeof(int), stream);
    k_part<<<PART_G, PART_B, 0, stream>>>(src, dst, cursor, packed);
    k_bsort<<<NBUCK, 256, 0, stream>>>(packed, cursor, srcsort, rowinfo, dinv);

    // --- layer 1 transform ---
    k_gemm<64, 48, 12><<<GB, 256, 0, stream>>>(x, W1, dinv, Hh, NN);
    // --- fused: layer-1 aggregation + relu/b1 + GEMM2 + dinv ---
    k_fused48<<<GB, 256, 0, stream>>>(Hh, rowinfo, srcsort, dinv, b1, W2, Hh2);
    // --- layer-2 aggregation (+b2) ---
    k_agg<32><<<(NN * 4 + B - 1) / B, B, 0, stream>>>(Hh2, rowinfo, srcsort, dinv, b2, out);
}